// Round 5
// baseline (3360.855 us; speedup 1.0000x reference)
//
#include <hip/hip_runtime.h>

// Problem: B,C,H,W = 16,256,32,32; K=16384. N = B*H*W = 16384 rows.
#define KCODES  16384
#define NPOS    16384

// ws float offsets (total ~12.63M floats = 50.5 MB)
#define OFF_XT    0           // [N][256] packed x (row-major "flat") — for k5/rownorm
#define OFF_XC    4194304     // [256][N] x transposed — x-tile load side of k2
#define OFF_WT    8388608     // [256][K] weight transposed — LDS staging side of k2
#define OFF_WN    12582912    // [K]  |w|^2
#define OFF_NS1   12599296    // [N] -|f|^2
#define OFF_IDX   12615680    // [N] argmax index (int)
#define OFF_SUMS  12632064    // [2] {sum mask, sum masked err^2}

#define OUT_LOSS  4194304
#define OUT_IND   4194305

#define AS1 __attribute__((address_space(1)))
#define AS3 __attribute__((address_space(3)))

// k2 tiling
#define BM 32        // rows per block = 4 waves x TM
#define TM 8         // rows per wave
#define BN 512       // k-chunk per block
#define CS 16        // c per LDS slice

// ---------- K1a: pack x (B,C,HW) -> xt[N][256] via LDS tile transpose ----------
__global__ void k1a_pack_x(const float* __restrict__ x, float* __restrict__ xt)
{
    __shared__ float t[32][33];
    const int p0 = blockIdx.x * 32, c0 = blockIdx.y * 32, b = blockIdx.z;
    const int tx = threadIdx.x, ty = threadIdx.y;   // 32 x 8
#pragma unroll
    for (int i = 0; i < 4; ++i) {
        int cl = ty + i * 8;
        t[cl][tx] = x[(b * 256 + c0 + cl) * 1024 + p0 + tx];
    }
    __syncthreads();
#pragma unroll
    for (int i = 0; i < 4; ++i) {
        int pl = ty + i * 8;
        xt[(b * 1024 + p0 + pl) * 256 + c0 + tx] = t[tx][pl];
    }
}

// ---------- K1c: x (B,C,HW) -> xc[c][b*1024+hw] (pure coalesced permute) ----------
__global__ void k1c_pack_xc(const float4* __restrict__ x4, float4* __restrict__ xc4)
{
    const int b = blockIdx.x >> 8, c = blockIdx.x & 255;
    xc4[(c * 16384 + b * 1024) / 4 + threadIdx.x] = x4[(b * 256 + c) * 256 + threadIdx.x];
}

// ---------- K1b: weight[K][256] -> wt[256][K] via LDS tile transpose ----------
__global__ void k1b_pack_w(const float* __restrict__ w, float* __restrict__ wt)
{
    __shared__ float t[32][33];
    const int k0 = blockIdx.x * 32, c0 = blockIdx.y * 32;
    const int tx = threadIdx.x, ty = threadIdx.y;   // 32 x 8
#pragma unroll
    for (int i = 0; i < 4; ++i) {
        int kl = ty + i * 8;
        t[kl][tx] = w[(k0 + kl) * 256 + c0 + tx];
    }
    __syncthreads();
#pragma unroll
    for (int i = 0; i < 4; ++i) {
        int cl = ty + i * 8;
        wt[(c0 + cl) * 16384 + k0 + tx] = t[tx][cl];
    }
}

// ---------- Krn: numpy-pairwise fp32 sum of squares per 256-elem row ----------
__global__ void k_rownorm(const float4* __restrict__ src4, float* __restrict__ out,
                          float sign)
{
    __shared__ float4 rows[32 * 64];
    const int tid = threadIdx.x;
    const int r0 = blockIdx.x * 32;
#pragma unroll
    for (int i = 0; i < 8; ++i) rows[tid + 256 * i] = src4[r0 * 64 + tid + 256 * i];
    __syncthreads();
    const int rl = tid >> 3, j = tid & 7;
    const float* q = (const float*)&rows[rl * 64];
    float h[2];
#pragma unroll
    for (int half = 0; half < 2; ++half) {
        const float* p = q + half * 128;
        float x = p[j];
        float r = __fmul_rn(x, x);
#pragma unroll
        for (int i = 1; i < 16; ++i) {
            float y = p[8 * i + j];
            r = __fadd_rn(r, __fmul_rn(y, y));
        }
        float t = __fadd_rn(r, __shfl_xor(r, 1));
        t = __fadd_rn(t, __shfl_xor(t, 2));
        t = __fadd_rn(t, __shfl_xor(t, 4));
        h[half] = t;
    }
    if (j == 0) out[r0 + rl] = sign * __fadd_rn(h[0], h[1]);
}

// ---------- K2: fp32 GEMM + argmax of fl(fl(-s1 - wn_k) + 2*m_k) ----------
// Wave owns TM=8 rows; lanes own k-columns (8 each). x tile lives in 32 VGPRs,
// broadcast per (c,r) via v_readlane -> SGPR operand of v_fmac. w double-buffered
// in LDS via global_load_lds width-16.
// amdgpu_waves_per_eu(2,2): budget 256 VGPR/wave so the ~170-reg working set
// doesn't spill (LDS 64KB caps us at 2 blocks/CU regardless — r4 spilled 927MB
// to scratch because the allocator targeted the 128-VGPR/16-wave tier).
__global__ __launch_bounds__(256)
__attribute__((amdgpu_waves_per_eu(2, 2)))
void k2_gemm(
    const float* __restrict__ xc,   // [256][N]
    const float* __restrict__ wt,   // [256][K]
    const float* __restrict__ wn,   // [K]
    const float* __restrict__ ns1,  // [N]
    int* __restrict__ idx)
{
    __shared__ __align__(16) float wsl[2][CS * BN];   // 2 x 32 KB
    const int tid  = threadIdx.x;
    const int lane = tid & 63;
    const int wid  = tid >> 6;
    const int rowBase = blockIdx.x * BM + wid * TM;   // wave-uniform
    const int lane4 = lane * 4;

    // x tile: reg i, lane l holds xc[c][rowBase + (l&7)], c = ((l>>3)*2 + (i&1))*16 + (i>>1)
    float xt_reg[32];
#pragma unroll
    for (int i = 0; i < 32; ++i) {
        const int c = ((lane >> 3) * 2 + (i & 1)) * 16 + (i >> 1);
        xt_reg[i] = xc[c * 16384 + rowBase + (lane & 7)];
    }

    float ns1r[TM];
#pragma unroll
    for (int r = 0; r < TM; ++r) ns1r[r] = ns1[rowBase + r];

    float v1[TM]; int ki[TM];
#pragma unroll
    for (int r = 0; r < TM; ++r) { v1[r] = -3.0e38f; ki[r] = 0; }

    float acc[TM][8];
#pragma unroll
    for (int r = 0; r < TM; ++r)
#pragma unroll
        for (int j = 0; j < 8; ++j) acc[r][j] = 0.0f;

    // async stage of slice s into buffer buf (32 KB = 8 x 16B per thread)
    auto stage = [&](int s, int buf) {
        const int kc = s >> 4, cs = s & 15;
#pragma unroll
        for (int i = 0; i < 8; ++i) {
            const int o  = tid * 16 + i * 4096;       // byte offset in slice
            const int cl = o >> 11;                   // 0..15  (2KB per c-row)
            const int ko = (o & 2047) >> 2;           // 0..511
            const float* g = wt + (cs * CS + cl) * 16384 + kc * BN + ko;
            __builtin_amdgcn_global_load_lds(
                (const AS1 void*)g,
                (AS3 void*)((char*)&wsl[0][0] + buf * (CS * BN * 4) + o),
                16, 0, 0);
        }
    };

// one c-slice: P = slice parity (compile-time), csh = slice>>1 (runtime uniform)
#define COMPUTE_SLICE(P, WB)                                                   \
    {                                                                          \
        const float* wb_ = (WB);                                               \
        _Pragma("unroll")                                                      \
        for (int cl = 0; cl < 16; ++cl) {                                      \
            const float4 wa = *(const float4*)&wb_[cl * BN + lane4];           \
            const float4 wv = *(const float4*)&wb_[cl * BN + 256 + lane4];     \
            _Pragma("unroll")                                                  \
            for (int r = 0; r < TM; ++r) {                                     \
                const float xs = __int_as_float(__builtin_amdgcn_readlane(     \
                    __float_as_int(xt_reg[cl * 2 + (P)]), ln_base + r));       \
                acc[r][0] += xs * wa.x;  acc[r][1] += xs * wa.y;               \
                acc[r][2] += xs * wa.z;  acc[r][3] += xs * wa.w;               \
                acc[r][4] += xs * wv.x;  acc[r][5] += xs * wv.y;               \
                acc[r][6] += xs * wv.z;  acc[r][7] += xs * wv.w;               \
            }                                                                  \
        }                                                                      \
    }

    stage(0, 0);
    __syncthreads();

    for (int sc = 0; sc < 256; ++sc) {       // sc = chunk*8 + csh
        const int csh = sc & 7;
        const int ln_base = csh * 8;         // readlane base (uniform SGPR)
        const int s0 = sc * 2;

        // even slice (parity 0, buffer 0); prefetch odd slice into buffer 1
        stage(s0 + 1, 1);
        COMPUTE_SLICE(0, &wsl[0][0]);
        __syncthreads();

        // odd slice (parity 1, buffer 1); prefetch next even slice into buffer 0
        if (sc < 255) stage(s0 + 2, 0);
        COMPUTE_SLICE(1, &wsl[1][0]);

        if (csh == 7) {                      // chunk complete: fold argmax
            const int kb = (sc >> 3) * BN;
            const float4 wn0 = *(const float4*)&wn[kb + lane4];
            const float4 wn1 = *(const float4*)&wn[kb + 256 + lane4];
            const float wnj[8] = {wn0.x, wn0.y, wn0.z, wn0.w,
                                  wn1.x, wn1.y, wn1.z, wn1.w};
#pragma unroll
            for (int r = 0; r < TM; ++r)
#pragma unroll
                for (int j = 0; j < 8; ++j) {
                    // replicate np rounding: t1 = fl(-s1 - wn); d = fl(t1 + 2m)
                    const float t1 = __fadd_rn(ns1r[r], -wnj[j]);
                    const float d  = __fadd_rn(t1, __fmul_rn(2.0f, acc[r][j]));
                    const int  kk  = kb + (j >> 2) * 256 + lane4 + (j & 3);
                    if (d > v1[r]) { v1[r] = d; ki[r] = kk; }  // ascending k: first-wins
                    acc[r][j] = 0.0f;
                }
        }
        __syncthreads();
    }

    // cross-lane argmax merge per row (np tie-break: lowest index)
#pragma unroll
    for (int r = 0; r < TM; ++r) {
        float v = v1[r]; int k = ki[r];
#pragma unroll
        for (int off = 1; off < 64; off <<= 1) {
            const float ov = __shfl_xor(v, off, 64);
            const int   ok = __shfl_xor(k, off, 64);
            if (ov > v || (ov == v && ok < k)) { v = ov; k = ok; }
        }
        if (lane == 0) idx[rowBase + r] = k;
    }
#undef COMPUTE_SLICE
}

// ---------- K5: gather outputs + loss partials ----------
__global__ void k5_out(const float* __restrict__ xt, const float* __restrict__ weight,
                       const float* __restrict__ mask, const int* __restrict__ idx,
                       float* __restrict__ out, float* __restrict__ sums)
{
    __shared__ float red[4];
    const int n = blockIdx.x, c = threadIdx.x;
    const int id = idx[n];
    const float mval = mask[n];
    const float wq = weight[id * 256 + c];
    const float xv = xt[n * 256 + c];
    const int b = n >> 10, hw = n & 1023;
    out[(b * 256 + c) * 1024 + hw] = wq;
    float e = wq - xv;
    float v = mval * e * e;
    for (int o = 32; o > 0; o >>= 1) v += __shfl_down(v, o, 64);
    if ((c & 63) == 0) red[c >> 6] = v;
    __syncthreads();
    if (c == 0) {
        atomicAdd(&sums[1], red[0] + red[1] + red[2] + red[3]);
        atomicAdd(&sums[0], mval);
        out[OUT_IND + n] = (float)id;
    }
}

// ---------- K6: finalize loss ----------
__global__ void k6_final(const float* __restrict__ sums, float* __restrict__ out)
{
    if (threadIdx.x == 0)
        out[OUT_LOSS] = (float)(1.25 * (double)sums[1] / (256.0 * (double)sums[0]));
}

extern "C" void kernel_launch(void* const* d_in, const int* in_sizes, int n_in,
                              void* d_out, int out_size, void* d_ws, size_t ws_size,
                              hipStream_t stream)
{
    const float* x      = (const float*)d_in[0];   // [16,256,32,32]
    const float* mask   = (const float*)d_in[1];   // [16,1,32,32]
    const float* weight = (const float*)d_in[2];   // [16384,256]
    float* out = (float*)d_out;
    float* ws  = (float*)d_ws;

    float* xt   = ws + OFF_XT;
    float* xc   = ws + OFF_XC;
    float* wt   = ws + OFF_WT;
    float* wn   = ws + OFF_WN;
    float* ns1  = ws + OFF_NS1;
    int*   idx  = (int*)(ws + OFF_IDX);
    float* sums = ws + OFF_SUMS;

    hipMemsetAsync(sums, 0, 2 * sizeof(float), stream);
    k1a_pack_x<<<dim3(32, 8, 16), dim3(32, 8), 0, stream>>>(x, xt);
    k1c_pack_xc<<<4096, 256, 0, stream>>>((const float4*)x, (float4*)xc);
    k1b_pack_w<<<dim3(512, 8), dim3(32, 8), 0, stream>>>(weight, wt);
    k_rownorm<<<512, 256, 0, stream>>>((const float4*)xt, ns1, -1.0f);
    k_rownorm<<<512, 256, 0, stream>>>((const float4*)weight, wn, 1.0f);
    k2_gemm<<<512, 256, 0, stream>>>(xc, wt, wn, ns1, idx);
    k5_out<<<16384, 256, 0, stream>>>(xt, weight, mask, idx, out, sums);
    k6_final<<<1, 64, 0, stream>>>(sums, out);
}

// Round 6
// 2682.052 us; speedup vs baseline: 1.2531x; 1.2531x over previous
//
#include <hip/hip_runtime.h>

// Problem: B,C,H,W = 16,256,32,32; K=16384. N = B*H*W = 16384 rows.
#define KCODES  16384
#define NPOS    16384

// ws float offsets (total ~12.63M floats = 50.5 MB)
#define OFF_XT    0           // [N][256] packed x (row-major "flat") — for k5/rownorm
#define OFF_XC    4194304     // [256][N] x transposed — x-tile load side of k2
#define OFF_WT    8388608     // [256][K] weight transposed — LDS staging side of k2
#define OFF_WN    12582912    // [K]  |w|^2
#define OFF_NS1   12599296    // [N] -|f|^2
#define OFF_IDX   12615680    // [N] argmax index (int)
#define OFF_SUMS  12632064    // [2] {sum mask, sum masked err^2}

#define OUT_LOSS  4194304
#define OUT_IND   4194305

#define AS1 __attribute__((address_space(1)))
#define AS3 __attribute__((address_space(3)))

// k2 tiling
#define BM 32        // rows per block = 4 waves x TM
#define TM 8         // rows per wave
#define BN 512       // k-chunk per block
#define CS 16        // c per LDS slice

// ---------- K1a: pack x (B,C,HW) -> xt[N][256] via LDS tile transpose ----------
__global__ void k1a_pack_x(const float* __restrict__ x, float* __restrict__ xt)
{
    __shared__ float t[32][33];
    const int p0 = blockIdx.x * 32, c0 = blockIdx.y * 32, b = blockIdx.z;
    const int tx = threadIdx.x, ty = threadIdx.y;   // 32 x 8
#pragma unroll
    for (int i = 0; i < 4; ++i) {
        int cl = ty + i * 8;
        t[cl][tx] = x[(b * 256 + c0 + cl) * 1024 + p0 + tx];
    }
    __syncthreads();
#pragma unroll
    for (int i = 0; i < 4; ++i) {
        int pl = ty + i * 8;
        xt[(b * 1024 + p0 + pl) * 256 + c0 + tx] = t[tx][pl];
    }
}

// ---------- K1c: x (B,C,HW) -> xc[c][b*1024+hw] (pure coalesced permute) ----------
__global__ void k1c_pack_xc(const float4* __restrict__ x4, float4* __restrict__ xc4)
{
    const int b = blockIdx.x >> 8, c = blockIdx.x & 255;
    xc4[(c * 16384 + b * 1024) / 4 + threadIdx.x] = x4[(b * 256 + c) * 256 + threadIdx.x];
}

// ---------- K1b: weight[K][256] -> wt[256][K] via LDS tile transpose ----------
__global__ void k1b_pack_w(const float* __restrict__ w, float* __restrict__ wt)
{
    __shared__ float t[32][33];
    const int k0 = blockIdx.x * 32, c0 = blockIdx.y * 32;
    const int tx = threadIdx.x, ty = threadIdx.y;   // 32 x 8
#pragma unroll
    for (int i = 0; i < 4; ++i) {
        int kl = ty + i * 8;
        t[kl][tx] = w[(k0 + kl) * 256 + c0 + tx];
    }
    __syncthreads();
#pragma unroll
    for (int i = 0; i < 4; ++i) {
        int cl = ty + i * 8;
        wt[(c0 + cl) * 16384 + k0 + tx] = t[tx][cl];
    }
}

// ---------- Krn: numpy-pairwise fp32 sum of squares per 256-elem row ----------
__global__ void k_rownorm(const float4* __restrict__ src4, float* __restrict__ out,
                          float sign)
{
    __shared__ float4 rows[32 * 64];
    const int tid = threadIdx.x;
    const int r0 = blockIdx.x * 32;
#pragma unroll
    for (int i = 0; i < 8; ++i) rows[tid + 256 * i] = src4[r0 * 64 + tid + 256 * i];
    __syncthreads();
    const int rl = tid >> 3, j = tid & 7;
    const float* q = (const float*)&rows[rl * 64];
    float h[2];
#pragma unroll
    for (int half = 0; half < 2; ++half) {
        const float* p = q + half * 128;
        float x = p[j];
        float r = __fmul_rn(x, x);
#pragma unroll
        for (int i = 1; i < 16; ++i) {
            float y = p[8 * i + j];
            r = __fadd_rn(r, __fmul_rn(y, y));
        }
        float t = __fadd_rn(r, __shfl_xor(r, 1));
        t = __fadd_rn(t, __shfl_xor(t, 2));
        t = __fadd_rn(t, __shfl_xor(t, 4));
        h[half] = t;
    }
    if (j == 0) out[r0 + rl] = sign * __fadd_rn(h[0], h[1]);
}

// ---------- K2: fp32 GEMM + argmax of fl(fl(-s1 - wn_k) + 2*m_k) ----------
// Wave owns TM=8 rows; lanes own k-columns (8 each). x tile lives in 32 VGPRs,
// broadcast per (c,r) via v_readlane -> SGPR operand of v_fmac. w double-buffered
// in LDS via global_load_lds width-16.
// Register diet (r5 spilled 926MB at the allocator's 128-VGPR choice): persistent
// argmax state (v1, ki, ns1) lives in LDS, touched only at chunk folds. Hot set =
// xt_reg(32) + acc(64) + w frags(8) + addressing ~= 116 < 128 -> no spill.
__global__ __launch_bounds__(256, 2)
void k2_gemm(
    const float* __restrict__ xc,   // [256][N]
    const float* __restrict__ wt,   // [256][K]
    const float* __restrict__ wn,   // [K]
    const float* __restrict__ ns1,  // [N]
    int* __restrict__ idx)
{
    __shared__ __align__(16) float wsl[2][CS * BN];   // 2 x 32 KB
    __shared__ float          v1ls[TM * 256];         // 8 KB   [r][tid]
    __shared__ unsigned short kils[TM * 256];         // 4 KB   [r][tid], k < 16384
    __shared__ float          ns1ls[BM];              // 128 B
    const int tid  = threadIdx.x;
    const int lane = tid & 63;
    const int wid  = tid >> 6;
    const int rowBase = blockIdx.x * BM + wid * TM;   // wave-uniform
    const int lane4 = lane * 4;

    // x tile: reg i, lane l holds xc[c][rowBase + (l&7)], c = ((l>>3)*2 + (i&1))*16 + (i>>1)
    float xt_reg[32];
#pragma unroll
    for (int i = 0; i < 32; ++i) {
        const int c = ((lane >> 3) * 2 + (i & 1)) * 16 + (i >> 1);
        xt_reg[i] = xc[c * 16384 + rowBase + (lane & 7)];
    }

    float acc[TM][8];
#pragma unroll
    for (int r = 0; r < TM; ++r)
#pragma unroll
        for (int j = 0; j < 8; ++j) acc[r][j] = 0.0f;

    // async stage of slice s into buffer buf (32 KB = 8 x 16B per thread)
    auto stage = [&](int s, int buf) {
        const int kc = s >> 4, cs = s & 15;
#pragma unroll
        for (int i = 0; i < 8; ++i) {
            const int o  = tid * 16 + i * 4096;       // byte offset in slice
            const int cl = o >> 11;                   // 0..15  (2KB per c-row)
            const int ko = (o & 2047) >> 2;           // 0..511
            const float* g = wt + (cs * CS + cl) * 16384 + kc * BN + ko;
            __builtin_amdgcn_global_load_lds(
                (const AS1 void*)g,
                (AS3 void*)((char*)&wsl[0][0] + buf * (CS * BN * 4) + o),
                16, 0, 0);
        }
    };

// one c-slice: P = slice parity (compile-time), csh = slice>>1 (runtime uniform)
#define COMPUTE_SLICE(P, WB)                                                   \
    {                                                                          \
        const float* wb_ = (WB);                                               \
        _Pragma("unroll")                                                      \
        for (int cl = 0; cl < 16; ++cl) {                                      \
            const float4 wa = *(const float4*)&wb_[cl * BN + lane4];           \
            const float4 wv = *(const float4*)&wb_[cl * BN + 256 + lane4];     \
            _Pragma("unroll")                                                  \
            for (int r = 0; r < TM; ++r) {                                     \
                const float xs = __int_as_float(__builtin_amdgcn_readlane(     \
                    __float_as_int(xt_reg[cl * 2 + (P)]), ln_base + r));       \
                acc[r][0] += xs * wa.x;  acc[r][1] += xs * wa.y;               \
                acc[r][2] += xs * wa.z;  acc[r][3] += xs * wa.w;               \
                acc[r][4] += xs * wv.x;  acc[r][5] += xs * wv.y;               \
                acc[r][6] += xs * wv.z;  acc[r][7] += xs * wv.w;               \
            }                                                                  \
        }                                                                      \
    }

    stage(0, 0);
    if (tid < BM) ns1ls[tid] = ns1[blockIdx.x * BM + tid];
#pragma unroll
    for (int r = 0; r < TM; ++r) {
        v1ls[r * 256 + tid] = -3.0e38f;
        kils[r * 256 + tid] = 0;
    }
    __syncthreads();

    for (int sc = 0; sc < 256; ++sc) {       // sc = chunk*8 + csh
        const int csh = sc & 7;
        const int ln_base = csh * 8;         // readlane base (uniform SGPR)
        const int s0 = sc * 2;

        // even slice (parity 0, buffer 0); prefetch odd slice into buffer 1
        stage(s0 + 1, 1);
        COMPUTE_SLICE(0, &wsl[0][0]);
        __syncthreads();

        // odd slice (parity 1, buffer 1); prefetch next even slice into buffer 0
        if (sc < 255) stage(s0 + 2, 0);
        COMPUTE_SLICE(1, &wsl[1][0]);

        if (csh == 7) {                      // chunk complete: fold argmax (LDS state)
            const int kb = (sc >> 3) * BN;
            const float4 wn0 = *(const float4*)&wn[kb + lane4];
            const float4 wn1 = *(const float4*)&wn[kb + 256 + lane4];
            const float wnj[8] = {wn0.x, wn0.y, wn0.z, wn0.w,
                                  wn1.x, wn1.y, wn1.z, wn1.w};
#pragma unroll
            for (int r = 0; r < TM; ++r) {
                const float ns1v = ns1ls[wid * TM + r];
                float v = v1ls[r * 256 + tid];
                int   k = kils[r * 256 + tid];
#pragma unroll
                for (int j = 0; j < 8; ++j) {
                    // replicate np rounding: t1 = fl(-s1 - wn); d = fl(t1 + 2m)
                    const float t1 = __fadd_rn(ns1v, -wnj[j]);
                    const float d  = __fadd_rn(t1, __fmul_rn(2.0f, acc[r][j]));
                    const int  kk  = kb + (j >> 2) * 256 + lane4 + (j & 3);
                    if (d > v) { v = d; k = kk; }   // ascending k: first-wins
                    acc[r][j] = 0.0f;
                }
                v1ls[r * 256 + tid] = v;
                kils[r * 256 + tid] = (unsigned short)k;
            }
        }
        __syncthreads();
    }

    // cross-lane argmax merge per row (np tie-break: lowest index)
#pragma unroll
    for (int r = 0; r < TM; ++r) {
        float v = v1ls[r * 256 + tid];
        int   k = kils[r * 256 + tid];
#pragma unroll
        for (int off = 1; off < 64; off <<= 1) {
            const float ov = __shfl_xor(v, off, 64);
            const int   ok = __shfl_xor(k, off, 64);
            if (ov > v || (ov == v && ok < k)) { v = ov; k = ok; }
        }
        if (lane == 0) idx[rowBase + r] = k;
    }
#undef COMPUTE_SLICE
}

// ---------- K5: gather outputs + loss partials ----------
__global__ void k5_out(const float* __restrict__ xt, const float* __restrict__ weight,
                       const float* __restrict__ mask, const int* __restrict__ idx,
                       float* __restrict__ out, float* __restrict__ sums)
{
    __shared__ float red[4];
    const int n = blockIdx.x, c = threadIdx.x;
    const int id = idx[n];
    const float mval = mask[n];
    const float wq = weight[id * 256 + c];
    const float xv = xt[n * 256 + c];
    const int b = n >> 10, hw = n & 1023;
    out[(b * 256 + c) * 1024 + hw] = wq;
    float e = wq - xv;
    float v = mval * e * e;
    for (int o = 32; o > 0; o >>= 1) v += __shfl_down(v, o, 64);
    if ((c & 63) == 0) red[c >> 6] = v;
    __syncthreads();
    if (c == 0) {
        atomicAdd(&sums[1], red[0] + red[1] + red[2] + red[3]);
        atomicAdd(&sums[0], mval);
        out[OUT_IND + n] = (float)id;
    }
}

// ---------- K6: finalize loss ----------
__global__ void k6_final(const float* __restrict__ sums, float* __restrict__ out)
{
    if (threadIdx.x == 0)
        out[OUT_LOSS] = (float)(1.25 * (double)sums[1] / (256.0 * (double)sums[0]));
}

extern "C" void kernel_launch(void* const* d_in, const int* in_sizes, int n_in,
                              void* d_out, int out_size, void* d_ws, size_t ws_size,
                              hipStream_t stream)
{
    const float* x      = (const float*)d_in[0];   // [16,256,32,32]
    const float* mask   = (const float*)d_in[1];   // [16,1,32,32]
    const float* weight = (const float*)d_in[2];   // [16384,256]
    float* out = (float*)d_out;
    float* ws  = (float*)d_ws;

    float* xt   = ws + OFF_XT;
    float* xc   = ws + OFF_XC;
    float* wt   = ws + OFF_WT;
    float* wn   = ws + OFF_WN;
    float* ns1  = ws + OFF_NS1;
    int*   idx  = (int*)(ws + OFF_IDX);
    float* sums = ws + OFF_SUMS;

    hipMemsetAsync(sums, 0, 2 * sizeof(float), stream);
    k1a_pack_x<<<dim3(32, 8, 16), dim3(32, 8), 0, stream>>>(x, xt);
    k1c_pack_xc<<<4096, 256, 0, stream>>>((const float4*)x, (float4*)xc);
    k1b_pack_w<<<dim3(512, 8), dim3(32, 8), 0, stream>>>(weight, wt);
    k_rownorm<<<512, 256, 0, stream>>>((const float4*)xt, ns1, -1.0f);
    k_rownorm<<<512, 256, 0, stream>>>((const float4*)weight, wn, 1.0f);
    k2_gemm<<<512, 256, 0, stream>>>(xc, wt, wn, ns1, idx);
    k5_out<<<16384, 256, 0, stream>>>(xt, weight, mask, idx, out, sums);
    k6_final<<<1, 64, 0, stream>>>(sums, out);
}

// Round 7
// 2240.886 us; speedup vs baseline: 1.4998x; 1.1969x over previous
//
#include <hip/hip_runtime.h>

// Problem: B,C,H,W = 16,256,32,32; K=16384. N = B*H*W = 16384 rows.
#define KCODES  16384
#define NPOS    16384

// ws float offsets (total ~12.63M floats = 50.5 MB)
#define OFF_XT    0           // [N][256] packed x (row-major "flat") — for k5/rownorm
#define OFF_XC    4194304     // [256][N] x transposed — x-tile load side of k2
#define OFF_WT    8388608     // [256][K] weight transposed — LDS staging side of k2
#define OFF_WN    12582912    // [K]  |w|^2
#define OFF_NS1   12599296    // [N] -|f|^2
#define OFF_IDX   12615680    // [N] argmax index (int)
#define OFF_SUMS  12632064    // [2] {sum mask, sum masked err^2}

#define OUT_LOSS  4194304
#define OUT_IND   4194305

#define AS1 __attribute__((address_space(1)))
#define AS3 __attribute__((address_space(3)))

// k2 tiling
#define BM 32        // rows per block = 4 waves x TM
#define TM 8         // rows per wave
#define BN 512       // k-chunk per block
#define CS 16        // c per LDS slice

// ---------- K1a: pack x (B,C,HW) -> xt[N][256] via LDS tile transpose ----------
__global__ void k1a_pack_x(const float* __restrict__ x, float* __restrict__ xt)
{
    __shared__ float t[32][33];
    const int p0 = blockIdx.x * 32, c0 = blockIdx.y * 32, b = blockIdx.z;
    const int tx = threadIdx.x, ty = threadIdx.y;   // 32 x 8
#pragma unroll
    for (int i = 0; i < 4; ++i) {
        int cl = ty + i * 8;
        t[cl][tx] = x[(b * 256 + c0 + cl) * 1024 + p0 + tx];
    }
    __syncthreads();
#pragma unroll
    for (int i = 0; i < 4; ++i) {
        int pl = ty + i * 8;
        xt[(b * 1024 + p0 + pl) * 256 + c0 + tx] = t[tx][pl];
    }
}

// ---------- K1c: x (B,C,HW) -> xc[c][b*1024+hw] (pure coalesced permute) ----------
__global__ void k1c_pack_xc(const float4* __restrict__ x4, float4* __restrict__ xc4)
{
    const int b = blockIdx.x >> 8, c = blockIdx.x & 255;
    xc4[(c * 16384 + b * 1024) / 4 + threadIdx.x] = x4[(b * 256 + c) * 256 + threadIdx.x];
}

// ---------- K1b: weight[K][256] -> wt[256][K] via LDS tile transpose ----------
__global__ void k1b_pack_w(const float* __restrict__ w, float* __restrict__ wt)
{
    __shared__ float t[32][33];
    const int k0 = blockIdx.x * 32, c0 = blockIdx.y * 32;
    const int tx = threadIdx.x, ty = threadIdx.y;   // 32 x 8
#pragma unroll
    for (int i = 0; i < 4; ++i) {
        int kl = ty + i * 8;
        t[kl][tx] = w[(k0 + kl) * 256 + c0 + tx];
    }
    __syncthreads();
#pragma unroll
    for (int i = 0; i < 4; ++i) {
        int cl = ty + i * 8;
        wt[(c0 + cl) * 16384 + k0 + tx] = t[tx][cl];
    }
}

// ---------- Krn: numpy-pairwise fp32 sum of squares per 256-elem row ----------
__global__ void k_rownorm(const float4* __restrict__ src4, float* __restrict__ out,
                          float sign)
{
    __shared__ float4 rows[32 * 64];
    const int tid = threadIdx.x;
    const int r0 = blockIdx.x * 32;
#pragma unroll
    for (int i = 0; i < 8; ++i) rows[tid + 256 * i] = src4[r0 * 64 + tid + 256 * i];
    __syncthreads();
    const int rl = tid >> 3, j = tid & 7;
    const float* q = (const float*)&rows[rl * 64];
    float h[2];
#pragma unroll
    for (int half = 0; half < 2; ++half) {
        const float* p = q + half * 128;
        float x = p[j];
        float r = __fmul_rn(x, x);
#pragma unroll
        for (int i = 1; i < 16; ++i) {
            float y = p[8 * i + j];
            r = __fadd_rn(r, __fmul_rn(y, y));
        }
        float t = __fadd_rn(r, __shfl_xor(r, 1));
        t = __fadd_rn(t, __shfl_xor(t, 2));
        t = __fadd_rn(t, __shfl_xor(t, 4));
        h[half] = t;
    }
    if (j == 0) out[r0 + rl] = sign * __fadd_rn(h[0], h[1]);
}

// ---------- K2: fp32 GEMM + argmax of fl(fl(-s1 - wn_k) + 2*m_k) ----------
// Wave owns TM=8 rows; lanes own k-columns (8 each). x tile lives in 32 VGPRs,
// broadcast per (c,r) via v_readlane -> SGPR operand of v_fmac. w double-buffered
// in LDS via global_load_lds width-16. Persistent argmax state (v1/ki/ns1) in LDS
// (r6: kills the 128-VGPR-tier spill). __builtin_fmaf forces v_fmac — r6's
// `acc += xs*w` compiled to v_mul+v_add (VALU time 1924us == 2x FMA wall; this
// halves the hot-loop VALU instruction count).
__global__ __launch_bounds__(256, 2)
void k2_gemm(
    const float* __restrict__ xc,   // [256][N]
    const float* __restrict__ wt,   // [256][K]
    const float* __restrict__ wn,   // [K]
    const float* __restrict__ ns1,  // [N]
    int* __restrict__ idx)
{
    __shared__ __align__(16) float wsl[2][CS * BN];   // 2 x 32 KB
    __shared__ float          v1ls[TM * 256];         // 8 KB   [r][tid]
    __shared__ unsigned short kils[TM * 256];         // 4 KB   [r][tid], k < 16384
    __shared__ float          ns1ls[BM];              // 128 B
    const int tid  = threadIdx.x;
    const int lane = tid & 63;
    const int wid  = tid >> 6;
    const int rowBase = blockIdx.x * BM + wid * TM;   // wave-uniform
    const int lane4 = lane * 4;

    // x tile: reg i, lane l holds xc[c][rowBase + (l&7)], c = ((l>>3)*2 + (i&1))*16 + (i>>1)
    float xt_reg[32];
#pragma unroll
    for (int i = 0; i < 32; ++i) {
        const int c = ((lane >> 3) * 2 + (i & 1)) * 16 + (i >> 1);
        xt_reg[i] = xc[c * 16384 + rowBase + (lane & 7)];
    }

    float acc[TM][8];
#pragma unroll
    for (int r = 0; r < TM; ++r)
#pragma unroll
        for (int j = 0; j < 8; ++j) acc[r][j] = 0.0f;

    // async stage of slice s into buffer buf (32 KB = 8 x 16B per thread)
    auto stage = [&](int s, int buf) {
        const int kc = s >> 4, cs = s & 15;
#pragma unroll
        for (int i = 0; i < 8; ++i) {
            const int o  = tid * 16 + i * 4096;       // byte offset in slice
            const int cl = o >> 11;                   // 0..15  (2KB per c-row)
            const int ko = (o & 2047) >> 2;           // 0..511
            const float* g = wt + (cs * CS + cl) * 16384 + kc * BN + ko;
            __builtin_amdgcn_global_load_lds(
                (const AS1 void*)g,
                (AS3 void*)((char*)&wsl[0][0] + buf * (CS * BN * 4) + o),
                16, 0, 0);
        }
    };

// one c-slice: P = slice parity (compile-time), csh = slice>>1 (runtime uniform)
#define COMPUTE_SLICE(P, WB)                                                   \
    {                                                                          \
        const float* wb_ = (WB);                                               \
        _Pragma("unroll")                                                      \
        for (int cl = 0; cl < 16; ++cl) {                                      \
            const float4 wa = *(const float4*)&wb_[cl * BN + lane4];           \
            const float4 wv = *(const float4*)&wb_[cl * BN + 256 + lane4];     \
            _Pragma("unroll")                                                  \
            for (int r = 0; r < TM; ++r) {                                     \
                const float xs = __int_as_float(__builtin_amdgcn_readlane(     \
                    __float_as_int(xt_reg[cl * 2 + (P)]), ln_base + r));       \
                acc[r][0] = __builtin_fmaf(xs, wa.x, acc[r][0]);               \
                acc[r][1] = __builtin_fmaf(xs, wa.y, acc[r][1]);               \
                acc[r][2] = __builtin_fmaf(xs, wa.z, acc[r][2]);               \
                acc[r][3] = __builtin_fmaf(xs, wa.w, acc[r][3]);               \
                acc[r][4] = __builtin_fmaf(xs, wv.x, acc[r][4]);               \
                acc[r][5] = __builtin_fmaf(xs, wv.y, acc[r][5]);               \
                acc[r][6] = __builtin_fmaf(xs, wv.z, acc[r][6]);               \
                acc[r][7] = __builtin_fmaf(xs, wv.w, acc[r][7]);               \
            }                                                                  \
        }                                                                      \
    }

    stage(0, 0);
    if (tid < BM) ns1ls[tid] = ns1[blockIdx.x * BM + tid];
#pragma unroll
    for (int r = 0; r < TM; ++r) {
        v1ls[r * 256 + tid] = -3.0e38f;
        kils[r * 256 + tid] = 0;
    }
    __syncthreads();

    for (int sc = 0; sc < 256; ++sc) {       // sc = chunk*8 + csh
        const int csh = sc & 7;
        const int ln_base = csh * 8;         // readlane base (uniform SGPR)
        const int s0 = sc * 2;

        // even slice (parity 0, buffer 0); prefetch odd slice into buffer 1
        stage(s0 + 1, 1);
        COMPUTE_SLICE(0, &wsl[0][0]);
        __syncthreads();

        // odd slice (parity 1, buffer 1); prefetch next even slice into buffer 0
        if (sc < 255) stage(s0 + 2, 0);
        COMPUTE_SLICE(1, &wsl[1][0]);

        if (csh == 7) {                      // chunk complete: fold argmax (LDS state)
            const int kb = (sc >> 3) * BN;
            const float4 wn0 = *(const float4*)&wn[kb + lane4];
            const float4 wn1 = *(const float4*)&wn[kb + 256 + lane4];
            const float wnj[8] = {wn0.x, wn0.y, wn0.z, wn0.w,
                                  wn1.x, wn1.y, wn1.z, wn1.w};
#pragma unroll
            for (int r = 0; r < TM; ++r) {
                const float ns1v = ns1ls[wid * TM + r];
                float v = v1ls[r * 256 + tid];
                int   k = kils[r * 256 + tid];
#pragma unroll
                for (int j = 0; j < 8; ++j) {
                    // replicate np rounding: t1 = fl(-s1 - wn); d = fl(t1 + 2m)
                    const float t1 = __fadd_rn(ns1v, -wnj[j]);
                    const float d  = __fadd_rn(t1, __fmul_rn(2.0f, acc[r][j]));
                    const int  kk  = kb + (j >> 2) * 256 + lane4 + (j & 3);
                    if (d > v) { v = d; k = kk; }   // ascending k: first-wins
                    acc[r][j] = 0.0f;
                }
                v1ls[r * 256 + tid] = v;
                kils[r * 256 + tid] = (unsigned short)k;
            }
        }
        __syncthreads();
    }

    // cross-lane argmax merge per row (np tie-break: lowest index)
#pragma unroll
    for (int r = 0; r < TM; ++r) {
        float v = v1ls[r * 256 + tid];
        int   k = kils[r * 256 + tid];
#pragma unroll
        for (int off = 1; off < 64; off <<= 1) {
            const float ov = __shfl_xor(v, off, 64);
            const int   ok = __shfl_xor(k, off, 64);
            if (ov > v || (ov == v && ok < k)) { v = ov; k = ok; }
        }
        if (lane == 0) idx[rowBase + r] = k;
    }
#undef COMPUTE_SLICE
}

// ---------- K5: gather outputs + loss partials ----------
__global__ void k5_out(const float* __restrict__ xt, const float* __restrict__ weight,
                       const float* __restrict__ mask, const int* __restrict__ idx,
                       float* __restrict__ out, float* __restrict__ sums)
{
    __shared__ float red[4];
    const int n = blockIdx.x, c = threadIdx.x;
    const int id = idx[n];
    const float mval = mask[n];
    const float wq = weight[id * 256 + c];
    const float xv = xt[n * 256 + c];
    const int b = n >> 10, hw = n & 1023;
    out[(b * 256 + c) * 1024 + hw] = wq;
    float e = wq - xv;
    float v = mval * e * e;
    for (int o = 32; o > 0; o >>= 1) v += __shfl_down(v, o, 64);
    if ((c & 63) == 0) red[c >> 6] = v;
    __syncthreads();
    if (c == 0) {
        atomicAdd(&sums[1], red[0] + red[1] + red[2] + red[3]);
        atomicAdd(&sums[0], mval);
        out[OUT_IND + n] = (float)id;
    }
}

// ---------- K6: finalize loss ----------
__global__ void k6_final(const float* __restrict__ sums, float* __restrict__ out)
{
    if (threadIdx.x == 0)
        out[OUT_LOSS] = (float)(1.25 * (double)sums[1] / (256.0 * (double)sums[0]));
}

extern "C" void kernel_launch(void* const* d_in, const int* in_sizes, int n_in,
                              void* d_out, int out_size, void* d_ws, size_t ws_size,
                              hipStream_t stream)
{
    const float* x      = (const float*)d_in[0];   // [16,256,32,32]
    const float* mask   = (const float*)d_in[1];   // [16,1,32,32]
    const float* weight = (const float*)d_in[2];   // [16384,256]
    float* out = (float*)d_out;
    float* ws  = (float*)d_ws;

    float* xt   = ws + OFF_XT;
    float* xc   = ws + OFF_XC;
    float* wt   = ws + OFF_WT;
    float* wn   = ws + OFF_WN;
    float* ns1  = ws + OFF_NS1;
    int*   idx  = (int*)(ws + OFF_IDX);
    float* sums = ws + OFF_SUMS;

    hipMemsetAsync(sums, 0, 2 * sizeof(float), stream);
    k1a_pack_x<<<dim3(32, 8, 16), dim3(32, 8), 0, stream>>>(x, xt);
    k1c_pack_xc<<<4096, 256, 0, stream>>>((const float4*)x, (float4*)xc);
    k1b_pack_w<<<dim3(512, 8), dim3(32, 8), 0, stream>>>(weight, wt);
    k_rownorm<<<512, 256, 0, stream>>>((const float4*)xt, ns1, -1.0f);
    k_rownorm<<<512, 256, 0, stream>>>((const float4*)weight, wn, 1.0f);
    k2_gemm<<<512, 256, 0, stream>>>(xc, wt, wn, ns1, idx);
    k5_out<<<16384, 256, 0, stream>>>(xt, weight, mask, idx, out, sums);
    k6_final<<<1, 64, 0, stream>>>(sums, out);
}